// Round 4
// baseline (105.648 us; speedup 1.0000x reference)
//
#include <hip/hip_runtime.h>

#define TT 48
#define II 5
#define HID 8

typedef float float2v __attribute__((ext_vector_type(2)));

// quad_perm DPP; 0xB1 = lane^1, 0x4E = lane^2, 0x1B = lane^3, 0x141 = row_half_mirror (lane^7 in 8-groups)
template<int CTRL>
__device__ __forceinline__ float dppf(float v) {
    return __int_as_float(__builtin_amdgcn_update_dpp(0, __float_as_int(v), CTRL, 0xF, 0xF, true));
}
__device__ __forceinline__ float fexp2(float x) {
    float r; asm("v_exp_f32 %0, %1" : "=v"(r) : "v"(x)); return r;
}
__device__ __forceinline__ float frcp(float x) { return __builtin_amdgcn_rcpf(x); }

// packed fp32 fma, weight broadcast via op_sel:
// pk_lo: lo = w.lo*x.lo + acc.lo ; hi = w.lo*x.hi + acc.hi   (broadcast w.lo)
// pk_hi: lo = w.hi*x.lo + acc.lo ; hi = w.hi*x.hi + acc.hi   (broadcast w.hi)
__device__ __forceinline__ float2v pk_lo(float2v acc, float2v w, float2v x) {
    asm("v_pk_fma_f32 %0, %1, %2, %0 op_sel_hi:[0,1,1]" : "+v"(acc) : "v"(w), "v"(x));
    return acc;
}
__device__ __forceinline__ float2v pk_hi(float2v acc, float2v w, float2v x) {
    asm("v_pk_fma_f32 %0, %1, %2, %0 op_sel:[1,0,0] op_sel_hi:[1,1,1]" : "+v"(acc) : "v"(w), "v"(x));
    return acc;
}
__device__ __forceinline__ float2v pk_lo3(float2v w, float2v x, float2v b) {
    float2v d;
    asm("v_pk_fma_f32 %0, %1, %2, %3 op_sel_hi:[0,1,1]" : "=v"(d) : "v"(w), "v"(x), "v"(b));
    return d;
}
__device__ __forceinline__ void pin2(float2v& v) { asm("" : "+v"(v)); }

__global__ __launch_bounds__(256, 3) void lstm_fused(
    const float* __restrict__ x,
    const float* __restrict__ W_ih,
    const float* __restrict__ W_hh,
    const float* __restrict__ b_ih,
    const float* __restrict__ b_hh,
    const float* __restrict__ fc_W,
    const float* __restrict__ fc_b,
    float* __restrict__ out, int B)
{
    __shared__ __align__(16) float s_fc[TT * HID];
    const int tid = threadIdx.x;
    for (int i = tid; i < TT * HID; i += 256) s_fc[i] = fc_W[i];
    __syncthreads();

    const int gt = blockIdx.x * 256 + tid;
    const int grp = gt >> 3;     // batch-pair group (8 lanes: 8 hidden units x 2 batches)
    const int q = gt & 7;        // owned hidden unit
    const int b0 = grp * 2;
    if (b0 >= B) return;

    const float L2E  = 1.44269504088896340736f;
    const float L2E2 = 2.0f * L2E;
    // i,f,o rows scaled by -log2e (sigmoid = rcp(1+exp2(s))), g rows by +2log2e.
    const float sc[4] = {-L2E, -L2E, L2E2, -L2E};

    // weights: wih[g][j] packs input-proj cols (2j,2j+1); w4p packs col4 of two gates;
    // whh[g][j] packs recurrent cols (q^(2j), q^(2j+1)) to match the DPP gather order.
    float2v wih[4][2], w4p[2], whh[4][4], biasp[4];
    #pragma unroll
    for (int g = 0; g < 4; ++g) {
        const int row = g * HID + q;
        wih[g][0] = (float2v){sc[g] * W_ih[row * II + 0], sc[g] * W_ih[row * II + 1]};
        wih[g][1] = (float2v){sc[g] * W_ih[row * II + 2], sc[g] * W_ih[row * II + 3]};
        #pragma unroll
        for (int j = 0; j < 4; ++j)
            whh[g][j] = (float2v){sc[g] * W_hh[row * HID + (q ^ (2 * j))],
                                  sc[g] * W_hh[row * HID + (q ^ (2 * j + 1))]};
        const float bb = sc[g] * (b_ih[row] + b_hh[row]);
        biasp[g] = (float2v){bb, bb};
    }
    w4p[0] = (float2v){sc[0] * W_ih[(0 * HID + q) * II + 4], sc[1] * W_ih[(1 * HID + q) * II + 4]};
    w4p[1] = (float2v){sc[2] * W_ih[(2 * HID + q) * II + 4], sc[3] * W_ih[(3 * HID + q) * II + 4]};

    #pragma unroll
    for (int g = 0; g < 4; ++g) {
        pin2(wih[g][0]); pin2(wih[g][1]); pin2(biasp[g]);
        #pragma unroll
        for (int j = 0; j < 4; ++j) pin2(whh[g][j]);
    }
    pin2(w4p[0]); pin2(w4p[1]);

    const float2* xA = reinterpret_cast<const float2*>(x + (size_t)b0 * (TT * II));
    const float2* xB = reinterpret_cast<const float2*>(x + (size_t)(b0 + 1) * (TT * II));

    float2 pA[5], pB[5];
    #pragma unroll
    for (int k = 0; k < 5; ++k) { pA[k] = xA[k]; pB[k] = xB[k]; }

    float2v c01 = (float2v){0.f, 0.f}, h01 = (float2v){0.f, 0.f};
    float accA = 0.f, accB = 0.f;

    #pragma unroll 1
    for (int ch = 0; ch < 24; ++ch) {       // 24 chunks x 2 timesteps
        float2v xp[10];
        #pragma unroll
        for (int k = 0; k < 5; ++k) {
            xp[2 * k]     = (float2v){pA[k].x, pB[k].x};
            xp[2 * k + 1] = (float2v){pA[k].y, pB[k].y};
        }
        const int nc = (ch < 23) ? ch + 1 : 23;
        #pragma unroll
        for (int k = 0; k < 5; ++k) { pA[k] = xA[nc * 5 + k]; pB[k] = xB[nc * 5 + k]; }

        #pragma unroll
        for (int s = 0; s < 2; ++s) {
            const int t = ch * 2 + s;
            const float2v* xs = &xp[s * 5];

            // gather the group's 8 h-pairs (pure-VALU DPP; slot m = unit q^m)
            float2v hap1 = (float2v){dppf<0xB1>(h01.x),  dppf<0xB1>(h01.y)};
            float2v hap2 = (float2v){dppf<0x4E>(h01.x),  dppf<0x4E>(h01.y)};
            float2v hap3 = (float2v){dppf<0x1B>(h01.x),  dppf<0x1B>(h01.y)};
            float2v hap7 = (float2v){dppf<0x141>(h01.x), dppf<0x141>(h01.y)};
            float2v hap6 = (float2v){dppf<0x141>(hap1.x), dppf<0x141>(hap1.y)};
            float2v hap5 = (float2v){dppf<0x141>(hap2.x), dppf<0x141>(hap2.y)};
            float2v hap4 = (float2v){dppf<0x141>(hap3.x), dppf<0x141>(hap3.y)};

            float2v gg[4];
            #pragma unroll
            for (int g = 0; g < 4; ++g) {
                float2v a = pk_lo3(wih[g][0], xs[0], biasp[g]);
                a = pk_hi(a, wih[g][0], xs[1]);
                a = pk_lo(a, wih[g][1], xs[2]);
                a = pk_hi(a, wih[g][1], xs[3]);
                a = (g & 1) ? pk_hi(a, w4p[g >> 1], xs[4]) : pk_lo(a, w4p[g >> 1], xs[4]);
                a = pk_lo(a, whh[g][0], h01);
                a = pk_hi(a, whh[g][0], hap1);
                a = pk_lo(a, whh[g][1], hap2);
                a = pk_hi(a, whh[g][1], hap3);
                a = pk_lo(a, whh[g][2], hap4);
                a = pk_hi(a, whh[g][2], hap5);
                a = pk_lo(a, whh[g][3], hap6);
                a = pk_hi(a, whh[g][3], hap7);
                gg[g] = a;
            }

            const float si0 = frcp(1.f + fexp2(gg[0].x)), si1 = frcp(1.f + fexp2(gg[0].y));
            const float sf0 = frcp(1.f + fexp2(gg[1].x)), sf1 = frcp(1.f + fexp2(gg[1].y));
            const float tg0 = fmaf(-2.f, frcp(1.f + fexp2(gg[2].x)), 1.f);
            const float tg1 = fmaf(-2.f, frcp(1.f + fexp2(gg[2].y)), 1.f);
            const float so0 = frcp(1.f + fexp2(gg[3].x)), so1 = frcp(1.f + fexp2(gg[3].y));

            c01.x = fmaf(sf0, c01.x, si0 * tg0);
            c01.y = fmaf(sf1, c01.y, si1 * tg1);
            const float tc0 = fmaf(-2.f, frcp(1.f + fexp2(c01.x * L2E2)), 1.f);
            const float tc1 = fmaf(-2.f, frcp(1.f + fexp2(c01.y * L2E2)), 1.f);
            h01.x = so0 * tc0;
            h01.y = so1 * tc1;

            const float fcw = s_fc[t * HID + q];
            accA = fmaf(h01.x, fcw, accA);
            accB = fmaf(h01.y, fcw, accB);
        }
    }

    accA += dppf<0xB1>(accA); accA += dppf<0x4E>(accA); accA += dppf<0x141>(accA);
    accB += dppf<0xB1>(accB); accB += dppf<0x4E>(accB); accB += dppf<0x141>(accB);
    if (q == 0) {
        float2 o2 = {accA + fc_b[0], accB + fc_b[0]};
        *reinterpret_cast<float2*>(out + b0) = o2;
    }
}

extern "C" void kernel_launch(void* const* d_in, const int* in_sizes, int n_in,
                              void* d_out, int out_size, void* d_ws, size_t ws_size,
                              hipStream_t stream) {
    const float* x    = (const float*)d_in[0];
    const float* W_ih = (const float*)d_in[1];
    const float* W_hh = (const float*)d_in[2];
    const float* b_ih = (const float*)d_in[3];
    const float* b_hh = (const float*)d_in[4];
    const float* fc_W = (const float*)d_in[5];
    const float* fc_b = (const float*)d_in[6];
    float* out = (float*)d_out;

    const int B = in_sizes[0] / (TT * II);
    const long long threads = (long long)(B / 2) * 8;
    const int grid = (int)((threads + 255) / 256);
    lstm_fused<<<grid, 256, 0, stream>>>(x, W_ih, W_hh, b_ih, b_hh, fc_W, fc_b, out, B);
}